// Round 4
// baseline (1905.942 us; speedup 1.0000x reference)
//
#include <hip/hip_runtime.h>
#include <hip/hip_bf16.h>

typedef unsigned short u16;
typedef __attribute__((ext_vector_type(8))) short   short8;
typedef __attribute__((ext_vector_type(8))) __bf16  bf16x8;
typedef __attribute__((ext_vector_type(16))) float  floatx16;

#define DD  128   // D
#define FE  16    // edge feature dim
#define DIN 145   // D + Fe + 1
#define K1  160   // Din padded to multiple of 16
#define K1P 168   // packed/xs row stride (shorts): 336 B = 21 granules, coprime 32 -> conflict-free
#define HQ  256   // hidden width
#define HQP 264   // h1 LDS row stride (shorts): 528 B = 33 granules -> conflict-free
#define ME  64    // edges per tile   (E = 1,000,000 divisible by 64)
#define MV  64    // variables per block (V = 200,000 divisible by 64)
#define EGRID 2048

__device__ __forceinline__ float logsig(float x) {
    return fminf(x, 0.f) - __logf(1.f + __expf(-fabsf(x)));
}
// f32 -> bf16 RNE (bit trick; inputs are finite)
__device__ __forceinline__ u16 f2b(float f) {
    union { float f; unsigned u; } x; x.f = f;
    unsigned r = x.u + 0x7fffu + ((x.u >> 16) & 1u);
    return (u16)(r >> 16);
}
__device__ __forceinline__ ushort4 f2b4(float4 v) {
    ushort4 o; o.x = f2b(v.x); o.y = f2b(v.y); o.z = f2b(v.z); o.w = f2b(v.w);
    return o;
}
__device__ __forceinline__ bf16x8 ld_bf8_lds(const short* p) {
    return __builtin_bit_cast(bf16x8, *(const short8*)p);
}
__device__ __forceinline__ bf16x8 ld_bf8_glb(const short* p) {
    return __builtin_bit_cast(bf16x8, *(const short8*)p);
}
// async global->LDS 16B copy; lds base must be wave-uniform (HW adds lane*16)
__device__ __forceinline__ void load_lds16(const void* g, void* l) {
    __builtin_amdgcn_global_load_lds(
        (const __attribute__((address_space(1))) unsigned int*)g,
        (__attribute__((address_space(3))) unsigned int*)l, 16, 0, 0);
}

// ---------------------------------------------------------------------------
// Weight pre-conversion: f32 -> bf16 copies in workspace (re-done every call).
// W1m rows padded 145 -> 160 (zeros).
// ---------------------------------------------------------------------------
__global__ __launch_bounds__(256) void conv_weights(
    const float* __restrict__ W1m, const float* __restrict__ W2m,
    const float* __restrict__ W1a, const float* __restrict__ W2a,
    short* __restrict__ W1mb, short* __restrict__ W2mb,
    short* __restrict__ W1ab, short* __restrict__ W2ab)
{
    int i = blockIdx.x * 256 + threadIdx.x;
    if (i < 256 * K1) {                              // W1mb [256][160]
        int n = i / K1, k = i - n * K1;
        W1mb[i] = (k < DIN) ? (short)f2b(W1m[n * DIN + k]) : (short)0;
    } else if (i < 256 * K1 + 256 * HQ) {            // W2mb [256][256]
        int j = i - 256 * K1;
        W2mb[j] = (short)f2b(W2m[j]);
    } else if (i < 256 * K1 + 2 * 256 * HQ) {        // W1ab [256][256]
        int j = i - 256 * K1 - 256 * HQ;
        W1ab[j] = (short)f2b(W1a[j]);
    } else if (i < 256 * K1 + 2 * 256 * HQ + 128 * HQ) { // W2ab [128][256]
        int j = i - 256 * K1 - 2 * 256 * HQ;
        W2ab[j] = (short)f2b(W2a[j]);
    }
}

// ---------------------------------------------------------------------------
// Input pre-pack: packed[e][0:168] = [vs bf16 | ef bf16 | sign*sol | 0-pad |
// vidx int at shorts 164-165]. This is byte-identical to the edge kernel's
// desired xs LDS image, so edge staging is a pure linear global->LDS DMA.
// Streaming pass: reads 576 MB, writes 336 MB.
// ---------------------------------------------------------------------------
__global__ __launch_bounds__(256) void conv_pack(
    const float* __restrict__ vs, const float* __restrict__ ef,
    const float* __restrict__ sol, const int* __restrict__ vidx,
    const int* __restrict__ sgn, short* __restrict__ packed, int E)
{
    const int tid  = blockIdx.x * 256 + threadIdx.x;
    const int nthr = gridDim.x * 256;
    // vs: E x 32 float4 units
    for (long i = tid; i < (long)E * 32; i += nthr) {
        long e = i >> 5; int q = (int)(i & 31) << 2;
        float4 v = *(const float4*)&vs[(size_t)e * DD + q];
        *(ushort4*)&packed[(size_t)e * K1P + q] = f2b4(v);
    }
    // ef: E x 4 float4 units
    for (long i = tid; i < (long)E * 4; i += nthr) {
        long e = i >> 2; int q = (int)(i & 3) << 2;
        float4 v = *(const float4*)&ef[(size_t)e * FE + q];
        *(ushort4*)&packed[(size_t)e * K1P + DD + q] = f2b4(v);
    }
    // tail: signed solution col 144, zeros 145..167, vidx at shorts 164-165
    for (long e = tid; e < E; e += nthr) {
        int vI = vidx[e];
        u16 s  = f2b((float)sgn[e] * sol[vI]);
        int4 z0 = {(int)s, 0, 0, 0};   // shorts 144-151 (144 = sol, 145-151 = 0)
        int4 z1 = {0, 0, 0, 0};        // shorts 152-159
        int4 z2 = {0, 0, vI, 0};       // shorts 160-167 (vidx at 164-165)
        *(int4*)&packed[(size_t)e * K1P + 144] = z0;
        *(int4*)&packed[(size_t)e * K1P + 152] = z1;
        *(int4*)&packed[(size_t)e * K1P + 160] = z2;
    }
}

// ---------------------------------------------------------------------------
// Edge stage (MFMA), staged variant: per tile of 64 edges, the entire input
// (incl. sol column and vidx) arrives as ONE linear 21504-B global_load_lds
// DMA from packed[]. Grid-stride tile loop with xs double-buffer: prefetch of
// tile t+1 is issued at the top of layer-2(t) and drained by the end-of-tile
// __syncthreads (vmcnt(0) before s_barrier). 512 thr = 8 waves, wave owns 32
// hidden cols. LDS = 2*21504 + 33792 = 76800 B -> 2 blocks/CU (16 waves).
// mfma_f32_32x32x16_bf16 D layout: col=lane&31, row=(reg&3)+8*(reg>>2)+4*(lane>>5).
// ---------------------------------------------------------------------------
__global__ __launch_bounds__(512, 4) void edge_mfma_staged(
    const float* __restrict__ b1m,
    const short* __restrict__ W1mb, const short* __restrict__ W2mb,
    const short* __restrict__ packed, float* __restrict__ agg, int NT)
{
    __shared__ short xs[2][ME * K1P];   // 2 x 21504 B
    __shared__ short h1s[ME][HQP];      // 33792 B, conflict-free stride
    const int tid = threadIdx.x;
    const int wv = tid >> 6, lane = tid & 63;
    const int lr = lane & 31, lh = lane >> 5;
    const int n0 = wv * 32;

    int t = blockIdx.x;
    if (t >= NT) return;

    // linear DMA of one packed tile (21504 B) into xs[buf]
    auto stage = [&](int buf, int tt) {
        const char* src = (const char*)packed + (size_t)tt * (ME * K1P * 2);
        char* dst = (char*)&xs[buf][0];
        #pragma unroll
        for (int rnd = 0; rnd < 3; ++rnd) {
            int base = rnd * 8192 + wv * 1024;
            if (base < ME * K1P * 2)
                load_lds16(src + base + lane * 16, dst + base);
        }
    };

    stage(0, t);
    __syncthreads();                       // drains DMA (vmcnt 0) + barrier

    const float bn = b1m[n0 + lr];
    const short* Wb1 = W1mb + (size_t)(n0 + lr) * K1;
    const short* Wb2 = W2mb + (size_t)(n0 + lr) * HQ;

    int i = 0;
    while (true) {
        const short* xsc = &xs[i & 1][0];

        // ---- layer 1: [64 x 160] @ [160 x 32-chunk] ----
        floatx16 a0 = {}, a1 = {};
        #pragma unroll 2
        for (int ks = 0; ks < K1 / 16; ++ks) {
            int k = ks * 16 + lh * 8;
            bf16x8 A0 = ld_bf8_lds(&xsc[lr * K1P + k]);
            bf16x8 A1 = ld_bf8_lds(&xsc[(32 + lr) * K1P + k]);
            bf16x8 B  = ld_bf8_glb(&Wb1[k]);
            a0 = __builtin_amdgcn_mfma_f32_32x32x16_bf16(A0, B, a0, 0, 0, 0);
            a1 = __builtin_amdgcn_mfma_f32_32x32x16_bf16(A1, B, a1, 0, 0, 0);
        }
        #pragma unroll
        for (int r = 0; r < 16; ++r) {
            int row = (r & 3) + 8 * (r >> 2) + 4 * lh;
            h1s[row][n0 + lr]      = (short)f2b(logsig(a0[r] + bn));
            h1s[32 + row][n0 + lr] = (short)f2b(logsig(a1[r] + bn));
        }
        __syncthreads();

        // prefetch next tile into the other xs buffer (overlaps layer 2)
        int tn = t + gridDim.x;
        if (tn < NT) stage((i + 1) & 1, tn);

        // ---- layer 2: [64 x 256] @ [256 x 32-chunk] ----
        a0 = (floatx16){}; a1 = (floatx16){};
        #pragma unroll 2
        for (int ks = 0; ks < HQ / 16; ++ks) {
            int k = ks * 16 + lh * 8;
            bf16x8 A0 = ld_bf8_lds(&h1s[lr][k]);
            bf16x8 A1 = ld_bf8_lds(&h1s[32 + lr][k]);
            bf16x8 B  = ld_bf8_glb(&Wb2[k]);
            a0 = __builtin_amdgcn_mfma_f32_32x32x16_bf16(A0, B, a0, 0, 0, 0);
            a1 = __builtin_amdgcn_mfma_f32_32x32x16_bf16(A1, B, a1, 0, 0, 0);
        }
        // ---- epilogue: logsig + coalesced f32 atomics (vidx from xs pad) ----
        #pragma unroll
        for (int r = 0; r < 16; ++r) {
            int row = (r & 3) + 8 * (r >> 2) + 4 * lh;
            int va = *(const int*)&xsc[row * K1P + 164];
            int vb = *(const int*)&xsc[(32 + row) * K1P + 164];
            atomicAdd(&agg[(size_t)va * HQ + n0 + lr], logsig(a0[r]));
            atomicAdd(&agg[(size_t)vb * HQ + n0 + lr], logsig(a1[r]));
        }
        if (tn >= NT) break;
        __syncthreads();                   // drains prefetch+atomics; guards h1s & xs
        t = tn; ++i;
    }
}

// ---------------------------------------------------------------------------
// Edge stage, legacy fallback (verified round-3 kernel): in-kernel gather +
// convert, used only if ws_size cannot hold packed[].
// ---------------------------------------------------------------------------
#define H1IDX(r, c) ((((r) * HQ) + (c)) ^ (((r) & 7) << 3))
__global__ __launch_bounds__(512, 6) void edge_mfma_legacy(
    const float* __restrict__ vs, const float* __restrict__ ef,
    const float* __restrict__ sol, const float* __restrict__ b1m,
    const short* __restrict__ W1mb, const short* __restrict__ W2mb,
    const int* __restrict__ vidx, const int* __restrict__ esign,
    float* __restrict__ agg, int E)
{
    __shared__ short xs[ME * K1P];
    __shared__ short h1s[ME * HQ];
    const int tid = threadIdx.x;
    const int e0 = blockIdx.x * ME;

    if (tid < ME) {
        int ge = e0 + tid;
        int v  = vidx[ge];
        *(int*)&xs[tid * K1P + 164] = v;
        xs[tid * K1P + 144] = (short)f2b((float)esign[ge] * sol[v]);
        #pragma unroll
        for (int k = 145; k < K1; ++k) xs[tid * K1P + k] = 0;
    }
    for (int i = tid; i < ME * 32; i += 512) {
        int e = i >> 5, q = (i & 31) << 2;
        float4 v = *(const float4*)&vs[(size_t)(e0 + e) * DD + q];
        *(ushort4*)&xs[e * K1P + q] = f2b4(v);
    }
    for (int i = tid; i < ME * 4; i += 512) {
        int e = i >> 2, q = (i & 3) << 2;
        float4 v = *(const float4*)&ef[(size_t)(e0 + e) * FE + q];
        *(ushort4*)&xs[e * K1P + DD + q] = f2b4(v);
    }
    __syncthreads();

    const int wv = tid >> 6, lane = tid & 63;
    const int lr = lane & 31, lh = lane >> 5;
    const int n0 = wv * 32;

    floatx16 a0 = {}, a1 = {};
    {
        const short* Wb = W1mb + (size_t)(n0 + lr) * K1;
        #pragma unroll 2
        for (int ks = 0; ks < K1 / 16; ++ks) {
            int k = ks * 16 + lh * 8;
            bf16x8 A0 = ld_bf8_lds(&xs[lr * K1P + k]);
            bf16x8 A1 = ld_bf8_lds(&xs[(32 + lr) * K1P + k]);
            bf16x8 B  = ld_bf8_glb(&Wb[k]);
            a0 = __builtin_amdgcn_mfma_f32_32x32x16_bf16(A0, B, a0, 0, 0, 0);
            a1 = __builtin_amdgcn_mfma_f32_32x32x16_bf16(A1, B, a1, 0, 0, 0);
        }
    }
    {
        float bn = b1m[n0 + lr];
        #pragma unroll
        for (int r = 0; r < 16; ++r) {
            int row = (r & 3) + 8 * (r >> 2) + 4 * lh;
            h1s[H1IDX(row,      n0 + lr)] = (short)f2b(logsig(a0[r] + bn));
            h1s[H1IDX(32 + row, n0 + lr)] = (short)f2b(logsig(a1[r] + bn));
        }
    }
    __syncthreads();

    a0 = (floatx16){}; a1 = (floatx16){};
    {
        const short* Wb = W2mb + (size_t)(n0 + lr) * HQ;
        #pragma unroll 2
        for (int ks = 0; ks < HQ / 16; ++ks) {
            int k = ks * 16 + lh * 8;
            bf16x8 A0 = ld_bf8_lds(&h1s[H1IDX(lr,      k)]);
            bf16x8 A1 = ld_bf8_lds(&h1s[H1IDX(32 + lr, k)]);
            bf16x8 B  = ld_bf8_glb(&Wb[k]);
            a0 = __builtin_amdgcn_mfma_f32_32x32x16_bf16(A0, B, a0, 0, 0, 0);
            a1 = __builtin_amdgcn_mfma_f32_32x32x16_bf16(A1, B, a1, 0, 0, 0);
        }
    }
    #pragma unroll
    for (int r = 0; r < 16; ++r) {
        int row = (r & 3) + 8 * (r >> 2) + 4 * lh;
        int va = *(const int*)&xs[row * K1P + 164];
        int vb = *(const int*)&xs[(32 + row) * K1P + 164];
        atomicAdd(&agg[(size_t)va * HQ + n0 + lr], logsig(a0[r]));
        atomicAdd(&agg[(size_t)vb * HQ + n0 + lr], logsig(a1[r]));
    }
}

// ---------------------------------------------------------------------------
// Variable stage (MFMA): h = ls(ls(agg@W1a^T+b1a)@W2a^T); out = h@Wc^T + bc
// MV=64 variables per block, 512 thr = 8 waves, all waves active in both
// layers. hsv (f32 [64][132]) aliases as_s after layer 1.
// LDS = 2 x 33792 = 67584 B -> 2 blocks/CU.
// ---------------------------------------------------------------------------
__global__ __launch_bounds__(512, 4) void var_mfma(
    const float* __restrict__ agg, const float* __restrict__ b1a,
    const short* __restrict__ W1ab, const short* __restrict__ W2ab,
    const float* __restrict__ Wc, const float* __restrict__ bc,
    float* __restrict__ out, int V)
{
    __shared__ short smem[2][MV * HQP];             // 2 x 33792 B
    short (*as_s)[HQP] = (short(*)[HQP])&smem[0][0];
    short (*h1v)[HQP]  = (short(*)[HQP])&smem[1][0];
    float (*hsv)[DD + 4] = (float(*)[DD + 4])&smem[0][0];  // aliases as_s
    const int tid = threadIdx.x;
    const int v0 = blockIdx.x * MV;

    // ---- load agg tile (64 x 256 f32 = 4096 float4), convert to bf16 ----
    for (int i = tid; i < MV * 64; i += 512) {
        int v = i >> 6, q = (i & 63) << 2;
        float4 a = *(const float4*)&agg[(size_t)(v0 + v) * HQ + q];
        *(ushort4*)&as_s[v][q] = f2b4(a);
    }
    __syncthreads();

    const int wv = tid >> 6, lane = tid & 63;
    const int lr = lane & 31, lh = lane >> 5;
    const int n0 = wv * 32;

    // ---- layer 1: M=64 (2 row-blocks), N=32/wave, K=256 ----
    floatx16 c0 = {}, c1 = {};
    {
        const short* Wb = W1ab + (size_t)(n0 + lr) * HQ;
        #pragma unroll 2
        for (int ks = 0; ks < HQ / 16; ++ks) {
            int k = ks * 16 + lh * 8;
            bf16x8 A0 = ld_bf8_lds(&as_s[lr][k]);
            bf16x8 A1 = ld_bf8_lds(&as_s[32 + lr][k]);
            bf16x8 B  = ld_bf8_glb(&Wb[k]);
            c0 = __builtin_amdgcn_mfma_f32_32x32x16_bf16(A0, B, c0, 0, 0, 0);
            c1 = __builtin_amdgcn_mfma_f32_32x32x16_bf16(A1, B, c1, 0, 0, 0);
        }
    }
    {
        float bn = b1a[n0 + lr];
        #pragma unroll
        for (int r = 0; r < 16; ++r) {
            int row = (r & 3) + 8 * (r >> 2) + 4 * lh;
            h1v[row][n0 + lr]      = (short)f2b(logsig(c0[r] + bn));
            h1v[32 + row][n0 + lr] = (short)f2b(logsig(c1[r] + bn));
        }
    }
    __syncthreads();

    // ---- layer 2: M=64, N=128: wave = (row-half rh, col-group cg) ----
    {
        const int rh = wv >> 2, n0b = (wv & 3) * 32;
        floatx16 d0 = {};
        const short* Wb = W2ab + (size_t)(n0b + lr) * HQ;
        #pragma unroll 2
        for (int ks = 0; ks < HQ / 16; ++ks) {
            int k = ks * 16 + lh * 8;
            bf16x8 A = ld_bf8_lds(&h1v[rh * 32 + lr][k]);
            bf16x8 B = ld_bf8_glb(&Wb[k]);
            d0 = __builtin_amdgcn_mfma_f32_32x32x16_bf16(A, B, d0, 0, 0, 0);
        }
        #pragma unroll
        for (int r = 0; r < 16; ++r) {
            int row = (r & 3) + 8 * (r >> 2) + 4 * lh;
            hsv[rh * 32 + row][n0b + lr] = logsig(d0[r]);
        }
    }
    __syncthreads();

    // ---- classifier: out[v][p] = dot(Wc[p,:], h[v,:]) + bc[p] (f32) ----
    if (tid < MV * 2) {
        int v = tid >> 1, p = tid & 1;
        const float* wrow = Wc + (size_t)p * DD;
        float acc = bc[p];
        for (int k = 0; k < DD; k += 4) {
            float4 w4 = *(const float4*)&wrow[k];
            float4 h4 = *(const float4*)&hsv[v][k];
            acc = fmaf(w4.w, h4.w, fmaf(w4.z, h4.z, fmaf(w4.y, h4.y, fmaf(w4.x, h4.x, acc))));
        }
        out[(size_t)(v0 + v) * 2 + p] = acc;
    }
}

extern "C" void kernel_launch(void* const* d_in, const int* in_sizes, int n_in,
                              void* d_out, int out_size, void* d_ws, size_t ws_size,
                              hipStream_t stream) {
    const float* vs  = (const float*)d_in[0];   // [E,128] f32
    const float* ef  = (const float*)d_in[1];   // [E,16]
    const float* sol = (const float*)d_in[2];   // [V]
    const float* W1m = (const float*)d_in[3];   // [256,145]
    const float* b1m = (const float*)d_in[4];   // [256]
    const float* W2m = (const float*)d_in[5];   // [256,256]
    const float* W1a = (const float*)d_in[6];   // [256,256]
    const float* b1a = (const float*)d_in[7];   // [256]
    const float* W2a = (const float*)d_in[8];   // [128,256]
    const float* Wc  = (const float*)d_in[9];   // [2,128]
    const float* bc  = (const float*)d_in[10];  // [2]
    const int* vidx  = (const int*)d_in[11];    // [E]
    const int* sgn   = (const int*)d_in[12];    // [E]

    const int E = in_sizes[0] / DD;   // 1,000,000 (divisible by 64)
    const int V = in_sizes[2];        //   200,000 (divisible by 64)
    const int NT = E / ME;            // 15,625 tiles

    char* ws = (char*)d_ws;
    size_t off = 0;
    auto alloc = [&](size_t bytes) {
        char* p = ws + off;
        off = (off + bytes + 255) & ~(size_t)255;
        return p;
    };
    float* agg    = (float*)alloc((size_t)V * HQ * sizeof(float));   // 204.8 MB
    short* W1mb   = (short*)alloc((size_t)256 * K1 * 2);             //  80 KB
    short* W2mb   = (short*)alloc((size_t)256 * HQ * 2);             // 128 KB
    short* W1ab   = (short*)alloc((size_t)256 * HQ * 2);             // 128 KB
    short* W2ab   = (short*)alloc((size_t)128 * HQ * 2);             //  64 KB
    short* packed = (short*)alloc((size_t)E * K1P * 2);              // 336 MB (last)
    const bool use_pack = (off <= ws_size);

    hipMemsetAsync(agg, 0, (size_t)V * HQ * sizeof(float), stream);
    conv_weights<<<dim3(800), dim3(256), 0, stream>>>(
        W1m, W2m, W1a, W2a, W1mb, W2mb, W1ab, W2ab);

    if (use_pack) {
        conv_pack<<<dim3(EGRID), dim3(256), 0, stream>>>(
            vs, ef, sol, vidx, sgn, packed, E);
        edge_mfma_staged<<<dim3(EGRID), dim3(512), 0, stream>>>(
            b1m, W1mb, W2mb, packed, agg, NT);
    } else {
        edge_mfma_legacy<<<dim3(NT), dim3(512), 0, stream>>>(
            vs, ef, sol, b1m, W1mb, W2mb, vidx, sgn, agg, E);
    }
    var_mfma<<<dim3(V / MV), dim3(512), 0, stream>>>(
        agg, b1a, W1ab, W2ab, Wc, bc, (float*)d_out, V);
}